// Round 6
// baseline (698.554 us; speedup 1.0000x reference)
//
#include <hip/hip_runtime.h>

#define N_NODES 50000
#define N_EDGES 800000
#define D 128
#define NB 1024          // co-resident grid: 4 blocks/CU x 256 CU (LDS 34.9KB, VGPR<=128)
#define NT 256

typedef __attribute__((ext_vector_type(8))) short bf16x8;
typedef __attribute__((ext_vector_type(4))) float f32x4;
typedef __attribute__((ext_vector_type(4))) short short4v;

__device__ __forceinline__ short f2bf(float f) {
    unsigned u = __float_as_uint(f);
    unsigned r = u + 0x7FFFu + ((u >> 16) & 1u);   // RNE; inputs finite
    return (short)(r >> 16);
}
__device__ __forceinline__ float bf2f(short s) {
    return __uint_as_float(((unsigned)(unsigned short)s) << 16);
}

// Device-wide barrier: all NB blocks co-resident by construction.
// threadfence (agent, seq_cst) flushes/invalidates per-XCD L2 so non-atomic
// stores (support/offsets/cursor/pairs) are visible across XCDs.
__device__ __forceinline__ void grid_barrier(int* bar, int tid) {
    __syncthreads();
    if (tid == 0) {
        __threadfence();
        __hip_atomic_fetch_add(bar, 1, __ATOMIC_ACQ_REL, __HIP_MEMORY_SCOPE_AGENT);
        while (__hip_atomic_load(bar, __ATOMIC_ACQUIRE, __HIP_MEMORY_SCOPE_AGENT) < NB) {}
        __threadfence();
    }
    __syncthreads();
}

__global__ __launch_bounds__(NT, 4) void mega_kernel(
    const float* __restrict__ inp, const float* __restrict__ W,
    const float* __restrict__ bias, const float* __restrict__ alpha,
    const float* __restrict__ vals, const int* __restrict__ rows,
    const int* __restrict__ cols,
    short* __restrict__ support,     // bf16 [N][D]
    int* counts, int* flags, int* bar, int* blockAgg,
    int* offsets, int* cursor, int2* pairs,
    float* __restrict__ out)
{
    __shared__ short Wt[128][136];   // 34 KB: Wt[col][k] bf16 (padded rows)
    const int tid = threadIdx.x;
    const int bid = blockIdx.x;

    // ---------------- P1: GEMM (blocks < 782) + histogram (all blocks) ----
    const int nGemm = (N_NODES + 63) >> 6;   // 782 tiles of 64 rows
    if (bid < nGemm) {
        // stage W: coalesced fp32 read, transpose + bf16 convert into LDS
        #pragma unroll
        for (int i = 0; i < 16; ++i) {
            int lin = i * 1024 + tid * 4;    // linear into W[k][c]
            int k = lin >> 7, c = lin & 127;
            float4 w = *(const float4*)&W[lin];
            Wt[c + 0][k] = f2bf(w.x);
            Wt[c + 1][k] = f2bf(w.y);
            Wt[c + 2][k] = f2bf(w.z);
            Wt[c + 3][k] = f2bf(w.w);
        }
        __syncthreads();
        const int wid = tid >> 6, lane = tid & 63;
        const int lr = lane & 15;    // A-row / B-col / D-col
        const int lg = lane >> 4;    // k-group 0..3
        const int m0 = bid * 64 + wid * 16;
        int arow = m0 + lr;
        if (arow >= N_NODES) arow = 0;       // clamped rows feed only unstored D-rows
        const float* aptr = &inp[(size_t)arow * D + lg * 8];
        f32x4 acc[8] = {};
        #pragma unroll
        for (int kc = 0; kc < 4; ++kc) {
            float4 a0 = *(const float4*)(aptr + kc * 32);
            float4 a1 = *(const float4*)(aptr + kc * 32 + 4);
            bf16x8 af;
            af[0] = f2bf(a0.x); af[1] = f2bf(a0.y); af[2] = f2bf(a0.z); af[3] = f2bf(a0.w);
            af[4] = f2bf(a1.x); af[5] = f2bf(a1.y); af[6] = f2bf(a1.z); af[7] = f2bf(a1.w);
            #pragma unroll
            for (int t = 0; t < 8; ++t) {
                const bf16x8 bf = *(const bf16x8*)&Wt[t * 16 + lr][kc * 32 + lg * 8];
                acc[t] = __builtin_amdgcn_mfma_f32_16x16x32_bf16(af, bf, acc[t], 0, 0, 0);
            }
        }
        // D: col = lane&15, row = (lane>>4)*4 + reg; store bf16
        #pragma unroll
        for (int t = 0; t < 8; ++t) {
            #pragma unroll
            for (int r = 0; r < 4; ++r) {
                int orow = m0 + lg * 4 + r;
                if (orow < N_NODES)
                    support[(size_t)orow * D + t * 16 + lr] = f2bf(acc[t][r]);
            }
        }
    }
    for (int e = bid * NT + tid; e < N_EDGES; e += NB * NT)
        atomicAdd(&counts[rows[e]], 1);

    grid_barrier(&bar[0], tid);

    // ---------------- P2: exclusive scan with lookback (blocks < 196) -----
    const int nScan = (N_NODES + NT - 1) / NT;   // 196
    if (bid < nScan) {
        __shared__ int s[NT];
        __shared__ int prefix_s;
        const int gid = bid * NT + tid;
        int v = (gid < N_NODES) ? counts[gid] : 0;
        s[tid] = v;
        __syncthreads();
        #pragma unroll
        for (int d2 = 1; d2 < NT; d2 <<= 1) {
            int t2 = (tid >= d2) ? s[tid - d2] : 0;
            __syncthreads();
            s[tid] += t2;
            __syncthreads();
        }
        if (tid == 0) {
            __hip_atomic_store(&blockAgg[bid], s[NT - 1], __ATOMIC_RELAXED, __HIP_MEMORY_SCOPE_AGENT);
            __hip_atomic_store(&flags[bid], 1, __ATOMIC_RELEASE, __HIP_MEMORY_SCOPE_AGENT);
        }
        if (tid < 64) {      // wave 0: lookback over predecessors (all resident)
            int sum = 0;
            for (int j = tid; j < bid; j += 64) {
                while (__hip_atomic_load(&flags[j], __ATOMIC_ACQUIRE, __HIP_MEMORY_SCOPE_AGENT) == 0) {}
                sum += __hip_atomic_load(&blockAgg[j], __ATOMIC_RELAXED, __HIP_MEMORY_SCOPE_AGENT);
            }
            #pragma unroll
            for (int d2 = 1; d2 < 64; d2 <<= 1) sum += __shfl_xor(sum, d2);
            if (tid == 0) prefix_s = sum;
        }
        __syncthreads();
        if (gid < N_NODES) {
            int o = prefix_s + s[tid] - v;
            offsets[gid] = o;
            cursor[gid] = o;
        }
        if (gid == 0) offsets[N_NODES] = N_EDGES;
    }
    grid_barrier(&bar[1], tid);

    // ---------------- P3: scatter edges to CSR order (packed 8B pairs) ----
    for (int e = bid * NT + tid; e < N_EDGES; e += NB * NT) {
        int p = atomicAdd(&cursor[rows[e]], 1);
        int2 pk;
        pk.x = cols[e];
        pk.y = __float_as_int(vals[e]);
        pairs[p] = pk;
    }
    grid_barrier(&bar[2], tid);

    // ---------------- P4: per-row gather-reduce + fused epilogue ----------
    // one wave per row (grid-stride over 4096 resident waves); wave split in
    // two 32-lane halves, each li owns 4 bf16 cols (8B gather), 2 edges in
    // parallel, 4-deep unroll = 8 gathers in flight.
    {
        const float a0 = alpha[0], a1 = alpha[1];
        const float mm = fmaxf(a0, a1);
        const float e0 = __expf(a0 - mm), e1 = __expf(a1 - mm);
        const float inv = 1.f / (e0 + e1);
        const float g0 = e0 * inv, g1 = e1 * inv;

        const int lane = tid & 63;
        const int half = lane >> 5, li = lane & 31;
        const float4 b4 = *(const float4*)&bias[li * 4];
        const int wslot = (bid * NT + tid) >> 6;     // 0..4095

        for (int wv = wslot; wv < N_NODES; wv += NB * 4) {
            const int start = offsets[wv];
            const int end   = offsets[wv + 1];
            const float4 x = *(const float4*)&inp[(size_t)wv * D + li * 4];

            float4 acc = make_float4(0.f, 0.f, 0.f, 0.f);
            int e = start;
            for (; e + 8 <= end; e += 8) {
                int2 p0 = pairs[e + 0 + half];
                int2 p1 = pairs[e + 2 + half];
                int2 p2 = pairs[e + 4 + half];
                int2 p3 = pairs[e + 6 + half];
                short4v s0 = *(const short4v*)&support[(size_t)p0.x * D + li * 4];
                short4v s1 = *(const short4v*)&support[(size_t)p1.x * D + li * 4];
                short4v s2 = *(const short4v*)&support[(size_t)p2.x * D + li * 4];
                short4v s3 = *(const short4v*)&support[(size_t)p3.x * D + li * 4];
                float v0 = __int_as_float(p0.y), v1 = __int_as_float(p1.y);
                float v2 = __int_as_float(p2.y), v3 = __int_as_float(p3.y);
                acc.x += v0 * bf2f(s0[0]) + v1 * bf2f(s1[0]) + v2 * bf2f(s2[0]) + v3 * bf2f(s3[0]);
                acc.y += v0 * bf2f(s0[1]) + v1 * bf2f(s1[1]) + v2 * bf2f(s2[1]) + v3 * bf2f(s3[1]);
                acc.z += v0 * bf2f(s0[2]) + v1 * bf2f(s1[2]) + v2 * bf2f(s2[2]) + v3 * bf2f(s3[2]);
                acc.w += v0 * bf2f(s0[3]) + v1 * bf2f(s1[3]) + v2 * bf2f(s2[3]) + v3 * bf2f(s3[3]);
            }
            for (; e < end; e += 2) {
                int idx = e + half;
                int2 p = (idx < end) ? pairs[idx] : make_int2(0, 0);  // v=0 when invalid
                float v = __int_as_float(p.y);
                short4v s = *(const short4v*)&support[(size_t)p.x * D + li * 4];
                acc.x += v * bf2f(s[0]);
                acc.y += v * bf2f(s[1]);
                acc.z += v * bf2f(s[2]);
                acc.w += v * bf2f(s[3]);
            }

            acc.x += __shfl_xor(acc.x, 32);
            acc.y += __shfl_xor(acc.y, 32);
            acc.z += __shfl_xor(acc.z, 32);
            acc.w += __shfl_xor(acc.w, 32);

            float t0 = acc.x * g0 + x.x * g1 + b4.x;
            float t1 = acc.y * g0 + x.y * g1 + b4.y;
            float t2 = acc.z * g0 + x.z * g1 + b4.z;
            float t3 = acc.w * g0 + x.w * g1 + b4.w;
            float r0 = t0 > 0.f ? t0 : (__expf(t0) - 1.f);
            float r1 = t1 > 0.f ? t1 : (__expf(t1) - 1.f);
            float r2 = t2 > 0.f ? t2 : (__expf(t2) - 1.f);
            float r3 = t3 > 0.f ? t3 : (__expf(t3) - 1.f);

            float2 o = (half == 0) ? make_float2(r0, r1) : make_float2(r2, r3);
            *(float2*)&out[(size_t)wv * D + li * 4 + half * 2] = o;
        }
    }
}

extern "C" void kernel_launch(void* const* d_in, const int* in_sizes, int n_in,
                              void* d_out, int out_size, void* d_ws, size_t ws_size,
                              hipStream_t stream)
{
    const float* inp   = (const float*)d_in[0];
    const float* W     = (const float*)d_in[1];
    const float* bias  = (const float*)d_in[2];
    const float* alpha = (const float*)d_in[3];
    const float* vals  = (const float*)d_in[4];
    const int*   rows  = (const int*)d_in[5];
    const int*   cols  = (const int*)d_in[6];
    float* out = (float*)d_out;

    // workspace layout (~20 MB; no trailing backslashes in comments)
    short* support  = (short*)d_ws;                            // N*D bf16
    int*   counts   = (int*)(support + (size_t)N_NODES * D);   // N ints (memset)
    int*   flags    = counts + N_NODES;                        // 256 ints (memset)
    int*   bar      = flags + 256;                             // 8 ints (memset)
    int*   blockAgg = bar + 8;                                 // 256 ints
    int*   offsets  = blockAgg + 256;                          // N+1 ints
    int*   cursor   = offsets + N_NODES + 1;                   // N ints (+1 pad)
    int2*  pairs    = (int2*)(cursor + N_NODES + 1);           // E pairs, 8B-aligned

    // zero counts + flags + barrier counters in one contiguous memset
    (void)hipMemsetAsync(counts, 0, (size_t)(N_NODES + 256 + 8) * sizeof(int), stream);

    mega_kernel<<<NB, NT, 0, stream>>>(inp, W, bias, alpha, vals, rows, cols,
                                       support, counts, flags, bar, blockAgg,
                                       offsets, cursor, pairs, out);
}

// Round 7
// 552.084 us; speedup vs baseline: 1.2653x; 1.2653x over previous
//
#include <hip/hip_runtime.h>

#define N_NODES 50000
#define N_EDGES 800000
#define D 128
#define NB 1024          // co-resident grid: 4 blocks/CU x 256 CU (LDS 34.9KB, VGPR<=128)
#define NT 256

typedef __attribute__((ext_vector_type(8))) short bf16x8;
typedef __attribute__((ext_vector_type(4))) float f32x4;
typedef __attribute__((ext_vector_type(4))) short short4v;

__device__ __forceinline__ short f2bf(float f) {
    unsigned u = __float_as_uint(f);
    unsigned r = u + 0x7FFFu + ((u >> 16) & 1u);   // RNE; inputs finite
    return (short)(r >> 16);
}
__device__ __forceinline__ float bf2f(short s) {
    return __uint_as_float(((unsigned)(unsigned short)s) << 16);
}

// Device-wide barrier, all NB blocks co-resident by construction.
// CRITICAL: the spin uses RELAXED loads (agent-scope ACQUIRE emits an
// L1+L2 invalidate EVERY iteration on gfx950 -- 1000 spinning blocks kept
// all XCD L2s cold and made round 6 3x slower). One threadfence (wb) before
// the arrive, one threadfence (inv) after the spin exits.
__device__ __forceinline__ void grid_barrier(int* bar, int tid) {
    __syncthreads();
    if (tid == 0) {
        __threadfence();   // release: writeback XCD L2 so our stores are visible
        __hip_atomic_fetch_add(bar, 1, __ATOMIC_RELAXED, __HIP_MEMORY_SCOPE_AGENT);
        while (__hip_atomic_load(bar, __ATOMIC_RELAXED, __HIP_MEMORY_SCOPE_AGENT) < NB)
            __builtin_amdgcn_s_sleep(2);
        __threadfence();   // acquire: invalidate so we see other blocks' stores
    }
    __syncthreads();
}

__global__ __launch_bounds__(NT, 4) void mega_kernel(
    const float* __restrict__ inp, const float* __restrict__ W,
    const float* __restrict__ bias, const float* __restrict__ alpha,
    const float* __restrict__ vals, const int* __restrict__ rows,
    const int* __restrict__ cols,
    short* __restrict__ support,     // bf16 [N][D]
    int* counts, int* bar, unsigned long long* aggFlag,
    int* offsets, int* cursor, int2* pairs,
    float* __restrict__ out)
{
    __shared__ short Wt[128][136];   // 34 KB: Wt[col][k] bf16 (padded rows)
    const int tid = threadIdx.x;
    const int bid = blockIdx.x;

    // ---------------- P1: GEMM (blocks < 782) + histogram (all blocks) ----
    const int nGemm = (N_NODES + 63) >> 6;   // 782 tiles of 64 rows
    if (bid < nGemm) {
        #pragma unroll
        for (int i = 0; i < 16; ++i) {
            int lin = i * 1024 + tid * 4;    // linear into W[k][c]
            int k = lin >> 7, c = lin & 127;
            float4 w = *(const float4*)&W[lin];
            Wt[c + 0][k] = f2bf(w.x);
            Wt[c + 1][k] = f2bf(w.y);
            Wt[c + 2][k] = f2bf(w.z);
            Wt[c + 3][k] = f2bf(w.w);
        }
        __syncthreads();
        const int wid = tid >> 6, lane = tid & 63;
        const int lr = lane & 15;    // A-row / B-col / D-col
        const int lg = lane >> 4;    // k-group 0..3
        const int m0 = bid * 64 + wid * 16;
        int arow = m0 + lr;
        if (arow >= N_NODES) arow = 0;       // clamped rows feed only unstored D-rows
        const float* aptr = &inp[(size_t)arow * D + lg * 8];
        f32x4 acc[8] = {};
        #pragma unroll
        for (int kc = 0; kc < 4; ++kc) {
            float4 a0 = *(const float4*)(aptr + kc * 32);
            float4 a1 = *(const float4*)(aptr + kc * 32 + 4);
            bf16x8 af;
            af[0] = f2bf(a0.x); af[1] = f2bf(a0.y); af[2] = f2bf(a0.z); af[3] = f2bf(a0.w);
            af[4] = f2bf(a1.x); af[5] = f2bf(a1.y); af[6] = f2bf(a1.z); af[7] = f2bf(a1.w);
            #pragma unroll
            for (int t = 0; t < 8; ++t) {
                const bf16x8 bf = *(const bf16x8*)&Wt[t * 16 + lr][kc * 32 + lg * 8];
                acc[t] = __builtin_amdgcn_mfma_f32_16x16x32_bf16(af, bf, acc[t], 0, 0, 0);
            }
        }
        // D: col = lane&15, row = (lane>>4)*4 + reg; store bf16
        #pragma unroll
        for (int t = 0; t < 8; ++t) {
            #pragma unroll
            for (int r = 0; r < 4; ++r) {
                int orow = m0 + lg * 4 + r;
                if (orow < N_NODES)
                    support[(size_t)orow * D + t * 16 + lr] = f2bf(acc[t][r]);
            }
        }
    }
    for (int e = bid * NT + tid; e < N_EDGES; e += NB * NT)
        atomicAdd(&counts[rows[e]], 1);

    grid_barrier(&bar[0], tid);

    // ---------------- P2: exclusive scan with lookback (blocks < 196) -----
    // (flag, blocksum) packed in ONE 64-bit word -> relaxed spin, no acquire,
    // no per-iteration cache invalidates, no ordering hazard.
    const int nScan = (N_NODES + NT - 1) / NT;   // 196
    if (bid < nScan) {
        __shared__ int s[NT];
        __shared__ int prefix_s;
        const int gid = bid * NT + tid;
        int v = (gid < N_NODES) ? counts[gid] : 0;
        s[tid] = v;
        __syncthreads();
        #pragma unroll
        for (int d2 = 1; d2 < NT; d2 <<= 1) {
            int t2 = (tid >= d2) ? s[tid - d2] : 0;
            __syncthreads();
            s[tid] += t2;
            __syncthreads();
        }
        if (tid == 0) {
            unsigned long long pk = (1ULL << 63) | (unsigned long long)(unsigned)s[NT - 1];
            __hip_atomic_store(&aggFlag[bid], pk, __ATOMIC_RELAXED, __HIP_MEMORY_SCOPE_AGENT);
        }
        if (tid < 64) {      // wave 0: lookback over predecessors (all resident)
            int sum = 0;
            for (int j = tid; j < bid; j += 64) {
                unsigned long long pk;
                while (((pk = __hip_atomic_load(&aggFlag[j], __ATOMIC_RELAXED,
                                                __HIP_MEMORY_SCOPE_AGENT)) >> 63) == 0)
                    __builtin_amdgcn_s_sleep(1);
                sum += (int)(unsigned)(pk & 0xFFFFFFFFULL);
            }
            #pragma unroll
            for (int d2 = 1; d2 < 64; d2 <<= 1) sum += __shfl_xor(sum, d2);
            if (tid == 0) prefix_s = sum;
        }
        __syncthreads();
        if (gid < N_NODES) {
            int o = prefix_s + s[tid] - v;
            offsets[gid] = o;
            cursor[gid] = o;
        }
        if (gid == 0) offsets[N_NODES] = N_EDGES;
    }
    grid_barrier(&bar[1], tid);

    // ---------------- P3: scatter edges to CSR order (packed 8B pairs) ----
    for (int e = bid * NT + tid; e < N_EDGES; e += NB * NT) {
        int p = atomicAdd(&cursor[rows[e]], 1);
        int2 pk;
        pk.x = cols[e];
        pk.y = __float_as_int(vals[e]);
        pairs[p] = pk;
    }
    grid_barrier(&bar[2], tid);

    // ---------------- P4: per-row gather-reduce + fused epilogue ----------
    {
        const float a0 = alpha[0], a1 = alpha[1];
        const float mm = fmaxf(a0, a1);
        const float e0 = __expf(a0 - mm), e1 = __expf(a1 - mm);
        const float inv = 1.f / (e0 + e1);
        const float g0 = e0 * inv, g1 = e1 * inv;

        const int lane = tid & 63;
        const int half = lane >> 5, li = lane & 31;
        const float4 b4 = *(const float4*)&bias[li * 4];
        const int wslot = (bid * NT + tid) >> 6;     // 0..4095

        for (int wv = wslot; wv < N_NODES; wv += NB * 4) {
            const int start = offsets[wv];
            const int end   = offsets[wv + 1];
            const float4 x = *(const float4*)&inp[(size_t)wv * D + li * 4];

            float4 acc = make_float4(0.f, 0.f, 0.f, 0.f);
            int e = start;
            for (; e + 8 <= end; e += 8) {
                int2 p0 = pairs[e + 0 + half];
                int2 p1 = pairs[e + 2 + half];
                int2 p2 = pairs[e + 4 + half];
                int2 p3 = pairs[e + 6 + half];
                short4v s0 = *(const short4v*)&support[(size_t)p0.x * D + li * 4];
                short4v s1 = *(const short4v*)&support[(size_t)p1.x * D + li * 4];
                short4v s2 = *(const short4v*)&support[(size_t)p2.x * D + li * 4];
                short4v s3 = *(const short4v*)&support[(size_t)p3.x * D + li * 4];
                float v0 = __int_as_float(p0.y), v1 = __int_as_float(p1.y);
                float v2 = __int_as_float(p2.y), v3 = __int_as_float(p3.y);
                acc.x += v0 * bf2f(s0[0]) + v1 * bf2f(s1[0]) + v2 * bf2f(s2[0]) + v3 * bf2f(s3[0]);
                acc.y += v0 * bf2f(s0[1]) + v1 * bf2f(s1[1]) + v2 * bf2f(s2[1]) + v3 * bf2f(s3[1]);
                acc.z += v0 * bf2f(s0[2]) + v1 * bf2f(s1[2]) + v2 * bf2f(s2[2]) + v3 * bf2f(s3[2]);
                acc.w += v0 * bf2f(s0[3]) + v1 * bf2f(s1[3]) + v2 * bf2f(s2[3]) + v3 * bf2f(s3[3]);
            }
            for (; e < end; e += 2) {
                int idx = e + half;
                int2 p = (idx < end) ? pairs[idx] : make_int2(0, 0);  // v=0 when invalid
                float v = __int_as_float(p.y);
                short4v s = *(const short4v*)&support[(size_t)p.x * D + li * 4];
                acc.x += v * bf2f(s[0]);
                acc.y += v * bf2f(s[1]);
                acc.z += v * bf2f(s[2]);
                acc.w += v * bf2f(s[3]);
            }

            acc.x += __shfl_xor(acc.x, 32);
            acc.y += __shfl_xor(acc.y, 32);
            acc.z += __shfl_xor(acc.z, 32);
            acc.w += __shfl_xor(acc.w, 32);

            float t0 = acc.x * g0 + x.x * g1 + b4.x;
            float t1 = acc.y * g0 + x.y * g1 + b4.y;
            float t2 = acc.z * g0 + x.z * g1 + b4.z;
            float t3 = acc.w * g0 + x.w * g1 + b4.w;
            float r0 = t0 > 0.f ? t0 : (__expf(t0) - 1.f);
            float r1 = t1 > 0.f ? t1 : (__expf(t1) - 1.f);
            float r2 = t2 > 0.f ? t2 : (__expf(t2) - 1.f);
            float r3 = t3 > 0.f ? t3 : (__expf(t3) - 1.f);

            float2 o = (half == 0) ? make_float2(r0, r1) : make_float2(r2, r3);
            *(float2*)&out[(size_t)wv * D + li * 4 + half * 2] = o;
        }
    }
}

extern "C" void kernel_launch(void* const* d_in, const int* in_sizes, int n_in,
                              void* d_out, int out_size, void* d_ws, size_t ws_size,
                              hipStream_t stream)
{
    const float* inp   = (const float*)d_in[0];
    const float* W     = (const float*)d_in[1];
    const float* bias  = (const float*)d_in[2];
    const float* alpha = (const float*)d_in[3];
    const float* vals  = (const float*)d_in[4];
    const int*   rows  = (const int*)d_in[5];
    const int*   cols  = (const int*)d_in[6];
    float* out = (float*)d_out;

    // workspace layout (~20 MB; no trailing backslashes in comments)
    short* support  = (short*)d_ws;                            // N*D bf16
    int*   counts   = (int*)(support + (size_t)N_NODES * D);   // N ints (memset)
    int*   bar      = counts + N_NODES;                        // 8 ints (memset)
    unsigned long long* aggFlag = (unsigned long long*)(bar + 8); // 256 x 8B (memset)
    int*   offsets  = (int*)(aggFlag + 256);                   // N+1 ints
    int*   cursor   = offsets + N_NODES + 1;                   // N ints (+1 pad)
    int2*  pairs    = (int2*)(cursor + N_NODES + 1);           // E pairs, 8B-aligned

    // zero counts + barrier counters + aggFlag words in one contiguous memset
    (void)hipMemsetAsync(counts, 0, (size_t)(N_NODES + 8 + 512) * sizeof(int), stream);

    mega_kernel<<<NB, NT, 0, stream>>>(inp, W, bias, alpha, vals, rows, cols,
                                       support, counts, bar, aggFlag,
                                       offsets, cursor, pairs, out);
}

// Round 9
// 209.255 us; speedup vs baseline: 3.3383x; 2.6383x over previous
//
#include <hip/hip_runtime.h>

#define N_NODES 50000
#define N_EDGES 800000
#define D 128

typedef __attribute__((ext_vector_type(8))) short bf16x8;
typedef __attribute__((ext_vector_type(4))) float f32x4;
typedef __attribute__((ext_vector_type(4))) short short4v;

__device__ __forceinline__ short f2bf(float f) {
    unsigned u = __float_as_uint(f);
    unsigned r = u + 0x7FFFu + ((u >> 16) & 1u);   // RNE; inputs finite
    return (short)(r >> 16);
}
__device__ __forceinline__ float bf2f(short s) {
    return __uint_as_float(((unsigned)(unsigned short)s) << 16);
}

// ---------------------------------------------------------------------------
// Phase 1 (merged dispatch): blocks [0, nGemm) do support = inputs @ weight
// via bf16 MFMA (fp32 accum, bf16 store); blocks [nGemm, ...) histogram rows.
// ---------------------------------------------------------------------------
__global__ __launch_bounds__(256) void gemm_hist_kernel(
    const float* __restrict__ inp, const float* __restrict__ W,
    short* __restrict__ support, const int* __restrict__ rows,
    int* __restrict__ counts, int nGemmBlocks)
{
    if ((int)blockIdx.x >= nGemmBlocks) {
        int e = ((int)blockIdx.x - nGemmBlocks) * 256 + threadIdx.x;
        if (e < N_EDGES) atomicAdd(&counts[rows[e]], 1);
        return;
    }

    __shared__ short Wt[128][136];   // 34 KB: Wt[col][k] bf16 (padded rows)
    const int tid = threadIdx.x;

    #pragma unroll
    for (int i = 0; i < 16; ++i) {
        int lin = i * 1024 + tid * 4;        // linear into W[k][c]
        int k = lin >> 7, c = lin & 127;
        float4 w = *(const float4*)&W[lin];
        Wt[c + 0][k] = f2bf(w.x);
        Wt[c + 1][k] = f2bf(w.y);
        Wt[c + 2][k] = f2bf(w.z);
        Wt[c + 3][k] = f2bf(w.w);
    }
    __syncthreads();

    const int wid = tid >> 6, lane = tid & 63;
    const int lr = lane & 15;        // A-row / B-col / D-col
    const int lg = lane >> 4;        // k-group 0..3
    const int m0 = (int)blockIdx.x * 64 + wid * 16;

    int arow = m0 + lr;
    if (arow >= N_NODES) arow = 0;   // clamped rows feed only unstored D-rows
    const float* aptr = &inp[(size_t)arow * D + lg * 8];

    f32x4 acc[8] = {};
    #pragma unroll
    for (int kc = 0; kc < 4; ++kc) {
        float4 a0 = *(const float4*)(aptr + kc * 32);
        float4 a1 = *(const float4*)(aptr + kc * 32 + 4);
        bf16x8 af;
        af[0] = f2bf(a0.x); af[1] = f2bf(a0.y); af[2] = f2bf(a0.z); af[3] = f2bf(a0.w);
        af[4] = f2bf(a1.x); af[5] = f2bf(a1.y); af[6] = f2bf(a1.z); af[7] = f2bf(a1.w);
        #pragma unroll
        for (int t = 0; t < 8; ++t) {
            const bf16x8 bf = *(const bf16x8*)&Wt[t * 16 + lr][kc * 32 + lg * 8];
            acc[t] = __builtin_amdgcn_mfma_f32_16x16x32_bf16(af, bf, acc[t], 0, 0, 0);
        }
    }
    // D: col = lane&15, row = (lane>>4)*4 + reg; store bf16
    #pragma unroll
    for (int t = 0; t < 8; ++t) {
        #pragma unroll
        for (int r = 0; r < 4; ++r) {
            int orow = m0 + lg * 4 + r;
            if (orow < N_NODES)
                support[(size_t)orow * D + t * 16 + lr] = f2bf(acc[t][r]);
        }
    }
}

// ---------------------------------------------------------------------------
// Phase 2b: single-dispatch exclusive scan. Ticket-ordered lookback with
// (flag,sum) packed into ONE 64-bit word -> relaxed spin only (agent-scope
// acquire spins invalidate L1/L2 every iteration -- round 6's 3x regression).
// ---------------------------------------------------------------------------
__global__ __launch_bounds__(256) void scan_fused(
    const int* __restrict__ counts, int* __restrict__ offsets,
    int* __restrict__ cursor, unsigned long long* __restrict__ aggFlag,
    int* __restrict__ ticket)
{
    __shared__ int s[256];
    __shared__ int bid_s, prefix_s;
    if (threadIdx.x == 0) bid_s = atomicAdd(ticket, 1);   // arrival order
    __syncthreads();
    const int bid = bid_s;
    const int gid = bid * 256 + threadIdx.x;
    int v = (gid < N_NODES) ? counts[gid] : 0;
    s[threadIdx.x] = v;
    __syncthreads();
    #pragma unroll
    for (int d = 1; d < 256; d <<= 1) {
        int t = (threadIdx.x >= d) ? s[threadIdx.x - d] : 0;
        __syncthreads();
        s[threadIdx.x] += t;
        __syncthreads();
    }
    if (threadIdx.x == 0) {
        unsigned long long pk = (1ULL << 63) | (unsigned long long)(unsigned)s[255];
        __hip_atomic_store(&aggFlag[bid], pk, __ATOMIC_RELAXED, __HIP_MEMORY_SCOPE_AGENT);
    }
    if (threadIdx.x < 64) {          // wave 0: lookback over predecessors
        int sum = 0;
        for (int j = threadIdx.x; j < bid; j += 64) {
            unsigned long long pk;
            while (((pk = __hip_atomic_load(&aggFlag[j], __ATOMIC_RELAXED,
                                            __HIP_MEMORY_SCOPE_AGENT)) >> 63) == 0)
                __builtin_amdgcn_s_sleep(1);
            sum += (int)(unsigned)(pk & 0xFFFFFFFFULL);
        }
        #pragma unroll
        for (int d = 1; d < 64; d <<= 1) sum += __shfl_xor(sum, d);
        if (threadIdx.x == 0) prefix_s = sum;
    }
    __syncthreads();
    if (gid < N_NODES) {
        int o = prefix_s + s[threadIdx.x] - v;
        offsets[gid] = o;
        cursor[gid] = o;
    }
    if (gid == 0) offsets[N_NODES] = N_EDGES;
}

// ---------------------------------------------------------------------------
// Phase 2c: scatter edges into CSR order as packed 8B (col, val) pairs
// ---------------------------------------------------------------------------
__global__ __launch_bounds__(256) void scatter_kernel(
    const int* __restrict__ rows, const int* __restrict__ cols,
    const float* __restrict__ vals, int* __restrict__ cursor,
    int2* __restrict__ pairs)
{
    int e = blockIdx.x * 256 + threadIdx.x;
    if (e < N_EDGES) {
        int p = atomicAdd(&cursor[rows[e]], 1);
        int2 pk;
        pk.x = cols[e];
        pk.y = __float_as_int(vals[e]);
        pairs[p] = pk;
    }
}

// ---------------------------------------------------------------------------
// Phase 3: per-row gather-reduce on bf16 support + fused epilogue.
// One wave per row; two 32-lane halves each own 4 bf16 cols (8B gathers),
// processing edges e+half in parallel, 4-deep unroll = 8 gathers in flight;
// cross-half shfl_xor(32) reduce; coalesced float2 store.
// ---------------------------------------------------------------------------
__global__ __launch_bounds__(256) void agg_fused(
    const short* __restrict__ support, const int* __restrict__ offsets,
    const int2* __restrict__ pairs,
    const float* __restrict__ inp, const float* __restrict__ bias,
    const float* __restrict__ alpha, float* __restrict__ out)
{
    const int wv = (blockIdx.x * 256 + threadIdx.x) >> 6;
    const int lane = threadIdx.x & 63;
    if (wv >= N_NODES) return;
    const int half = lane >> 5;
    const int li = lane & 31;

    const int start = offsets[wv];
    const int end   = offsets[wv + 1];

    const float4 x = *(const float4*)&inp[(size_t)wv * D + li * 4];
    const float4 b4 = *(const float4*)&bias[li * 4];
    const float a0 = alpha[0], a1 = alpha[1];

    float4 acc = make_float4(0.f, 0.f, 0.f, 0.f);
    int e = start;
    for (; e + 8 <= end; e += 8) {
        int2 p0 = pairs[e + 0 + half];
        int2 p1 = pairs[e + 2 + half];
        int2 p2 = pairs[e + 4 + half];
        int2 p3 = pairs[e + 6 + half];
        short4v s0 = *(const short4v*)&support[(size_t)p0.x * D + li * 4];
        short4v s1 = *(const short4v*)&support[(size_t)p1.x * D + li * 4];
        short4v s2 = *(const short4v*)&support[(size_t)p2.x * D + li * 4];
        short4v s3 = *(const short4v*)&support[(size_t)p3.x * D + li * 4];
        float v0 = __int_as_float(p0.y), v1 = __int_as_float(p1.y);
        float v2 = __int_as_float(p2.y), v3 = __int_as_float(p3.y);
        acc.x += v0 * bf2f(s0[0]) + v1 * bf2f(s1[0]) + v2 * bf2f(s2[0]) + v3 * bf2f(s3[0]);
        acc.y += v0 * bf2f(s0[1]) + v1 * bf2f(s1[1]) + v2 * bf2f(s2[1]) + v3 * bf2f(s3[1]);
        acc.z += v0 * bf2f(s0[2]) + v1 * bf2f(s1[2]) + v2 * bf2f(s2[2]) + v3 * bf2f(s3[2]);
        acc.w += v0 * bf2f(s0[3]) + v1 * bf2f(s1[3]) + v2 * bf2f(s2[3]) + v3 * bf2f(s3[3]);
    }
    for (; e < end; e += 2) {
        int idx = e + half;
        int2 p = (idx < end) ? pairs[idx] : make_int2(0, 0);   // v=0 when invalid
        float v = __int_as_float(p.y);
        short4v s = *(const short4v*)&support[(size_t)p.x * D + li * 4];
        acc.x += v * bf2f(s[0]);
        acc.y += v * bf2f(s[1]);
        acc.z += v * bf2f(s[2]);
        acc.w += v * bf2f(s[3]);
    }

    acc.x += __shfl_xor(acc.x, 32);
    acc.y += __shfl_xor(acc.y, 32);
    acc.z += __shfl_xor(acc.z, 32);
    acc.w += __shfl_xor(acc.w, 32);

    const float m = fmaxf(a0, a1);
    const float e0 = __expf(a0 - m), e1 = __expf(a1 - m);
    const float inv = 1.f / (e0 + e1);
    const float g0 = e0 * inv, g1 = e1 * inv;

    float t0 = acc.x * g0 + x.x * g1 + b4.x;
    float t1 = acc.y * g0 + x.y * g1 + b4.y;
    float t2 = acc.z * g0 + x.z * g1 + b4.z;
    float t3 = acc.w * g0 + x.w * g1 + b4.w;
    float r0 = t0 > 0.f ? t0 : (__expf(t0) - 1.f);
    float r1 = t1 > 0.f ? t1 : (__expf(t1) - 1.f);
    float r2 = t2 > 0.f ? t2 : (__expf(t2) - 1.f);
    float r3 = t3 > 0.f ? t3 : (__expf(t3) - 1.f);

    float2 o = (half == 0) ? make_float2(r0, r1) : make_float2(r2, r3);
    *(float2*)&out[(size_t)wv * D + li * 4 + half * 2] = o;
}

extern "C" void kernel_launch(void* const* d_in, const int* in_sizes, int n_in,
                              void* d_out, int out_size, void* d_ws, size_t ws_size,
                              hipStream_t stream)
{
    const float* inp   = (const float*)d_in[0];
    const float* W     = (const float*)d_in[1];
    const float* bias  = (const float*)d_in[2];
    const float* alpha = (const float*)d_in[3];
    const float* vals  = (const float*)d_in[4];
    const int*   rows  = (const int*)d_in[5];
    const int*   cols  = (const int*)d_in[6];
    float* out = (float*)d_out;

    // workspace layout (~20 MB; no trailing backslashes in comments)
    short* support  = (short*)d_ws;                            // N*D bf16
    int*   counts   = (int*)(support + (size_t)N_NODES * D);   // N ints (memset)
    int*   ticket   = counts + N_NODES;                        // 1 int (memset)
    // +1 pad keeps aggFlag 8B-aligned (N even, so counts..ticket+pad = even ints)
    unsigned long long* aggFlag = (unsigned long long*)(ticket + 2); // 256 x 8B (memset)
    int*   offsets  = (int*)(aggFlag + 256);                   // N+1 ints
    int*   cursor   = offsets + N_NODES + 1;                   // N ints (+1 pad -> 8B align)
    int2*  pairs    = (int2*)(cursor + N_NODES + 1);           // E pairs, 8B-aligned

    const int nGemmBlocks = (N_NODES + 63) / 64;            // 782
    const int nEdgeBlocks = (N_EDGES + 255) / 256;          // 3125
    const int nScanBlocks = (N_NODES + 255) / 256;          // 196

    // zero counts + ticket + pad + aggFlag in one contiguous memset
    (void)hipMemsetAsync(counts, 0, (size_t)(N_NODES + 2 + 512) * sizeof(int), stream);

    gemm_hist_kernel<<<nGemmBlocks + nEdgeBlocks, 256, 0, stream>>>(
        inp, W, support, rows, counts, nGemmBlocks);
    scan_fused<<<nScanBlocks, 256, 0, stream>>>(counts, offsets, cursor,
                                                aggFlag, ticket);
    scatter_kernel<<<nEdgeBlocks, 256, 0, stream>>>(rows, cols, vals, cursor, pairs);
    agg_fused<<<(N_NODES * 64 + 255) / 256, 256, 0, stream>>>(
        support, offsets, pairs, inp, bias, alpha, out);
}

// Round 10
// 206.412 us; speedup vs baseline: 3.3843x; 1.0138x over previous
//
#include <hip/hip_runtime.h>

#define N_NODES 50000
#define N_EDGES 800000
#define D 128

typedef __attribute__((ext_vector_type(8))) short bf16x8;
typedef __attribute__((ext_vector_type(4))) float f32x4;
typedef __attribute__((ext_vector_type(4))) short short4v;

__device__ __forceinline__ short f2bf(float f) {
    unsigned u = __float_as_uint(f);
    unsigned r = u + 0x7FFFu + ((u >> 16) & 1u);   // RNE; inputs finite
    return (short)(r >> 16);
}
__device__ __forceinline__ float bf2f(short s) {
    return __uint_as_float(((unsigned)(unsigned short)s) << 16);
}

// ---------------------------------------------------------------------------
// Phase 1 (merged dispatch): blocks [0, nGemm) do support = inputs @ weight
// via bf16 MFMA (fp32 accum, bf16 store); blocks [nGemm, ...) histogram rows.
// ---------------------------------------------------------------------------
__global__ __launch_bounds__(256) void gemm_hist_kernel(
    const float* __restrict__ inp, const float* __restrict__ W,
    short* __restrict__ support, const int* __restrict__ rows,
    int* __restrict__ counts, int nGemmBlocks)
{
    if ((int)blockIdx.x >= nGemmBlocks) {
        int e = ((int)blockIdx.x - nGemmBlocks) * 256 + threadIdx.x;
        if (e < N_EDGES) atomicAdd(&counts[rows[e]], 1);
        return;
    }

    __shared__ short Wt[128][136];   // 34 KB: Wt[col][k] bf16 (padded rows)
    const int tid = threadIdx.x;

    #pragma unroll
    for (int i = 0; i < 16; ++i) {
        int lin = i * 1024 + tid * 4;        // linear into W[k][c]
        int k = lin >> 7, c = lin & 127;
        float4 w = *(const float4*)&W[lin];
        Wt[c + 0][k] = f2bf(w.x);
        Wt[c + 1][k] = f2bf(w.y);
        Wt[c + 2][k] = f2bf(w.z);
        Wt[c + 3][k] = f2bf(w.w);
    }
    __syncthreads();

    const int wid = tid >> 6, lane = tid & 63;
    const int lr = lane & 15;        // A-row / B-col / D-col
    const int lg = lane >> 4;        // k-group 0..3
    const int m0 = (int)blockIdx.x * 64 + wid * 16;

    int arow = m0 + lr;
    if (arow >= N_NODES) arow = 0;   // clamped rows feed only unstored D-rows
    const float* aptr = &inp[(size_t)arow * D + lg * 8];

    f32x4 acc[8] = {};
    #pragma unroll
    for (int kc = 0; kc < 4; ++kc) {
        float4 a0 = *(const float4*)(aptr + kc * 32);
        float4 a1 = *(const float4*)(aptr + kc * 32 + 4);
        bf16x8 af;
        af[0] = f2bf(a0.x); af[1] = f2bf(a0.y); af[2] = f2bf(a0.z); af[3] = f2bf(a0.w);
        af[4] = f2bf(a1.x); af[5] = f2bf(a1.y); af[6] = f2bf(a1.z); af[7] = f2bf(a1.w);
        #pragma unroll
        for (int t = 0; t < 8; ++t) {
            const bf16x8 bf = *(const bf16x8*)&Wt[t * 16 + lr][kc * 32 + lg * 8];
            acc[t] = __builtin_amdgcn_mfma_f32_16x16x32_bf16(af, bf, acc[t], 0, 0, 0);
        }
    }
    // D: col = lane&15, row = (lane>>4)*4 + reg; store bf16
    #pragma unroll
    for (int t = 0; t < 8; ++t) {
        #pragma unroll
        for (int r = 0; r < 4; ++r) {
            int orow = m0 + lg * 4 + r;
            if (orow < N_NODES)
                support[(size_t)orow * D + t * 16 + lr] = f2bf(acc[t][r]);
        }
    }
}

// ---------------------------------------------------------------------------
// Phase 2b: single-dispatch exclusive scan. Ticket-ordered lookback with
// (flag,sum) packed into ONE 64-bit word -> relaxed spin only (agent-scope
// acquire spins invalidate L1/L2 every iteration -- round 6's 3x regression).
// ---------------------------------------------------------------------------
__global__ __launch_bounds__(256) void scan_fused(
    const int* __restrict__ counts, int* __restrict__ offsets,
    int* __restrict__ cursor, unsigned long long* __restrict__ aggFlag,
    int* __restrict__ ticket)
{
    __shared__ int s[256];
    __shared__ int bid_s, prefix_s;
    if (threadIdx.x == 0) bid_s = atomicAdd(ticket, 1);   // arrival order
    __syncthreads();
    const int bid = bid_s;
    const int gid = bid * 256 + threadIdx.x;
    int v = (gid < N_NODES) ? counts[gid] : 0;
    s[threadIdx.x] = v;
    __syncthreads();
    #pragma unroll
    for (int d = 1; d < 256; d <<= 1) {
        int t = (threadIdx.x >= d) ? s[threadIdx.x - d] : 0;
        __syncthreads();
        s[threadIdx.x] += t;
        __syncthreads();
    }
    if (threadIdx.x == 0) {
        unsigned long long pk = (1ULL << 63) | (unsigned long long)(unsigned)s[255];
        __hip_atomic_store(&aggFlag[bid], pk, __ATOMIC_RELAXED, __HIP_MEMORY_SCOPE_AGENT);
    }
    if (threadIdx.x < 64) {          // wave 0: lookback over predecessors
        int sum = 0;
        for (int j = threadIdx.x; j < bid; j += 64) {
            unsigned long long pk;
            while (((pk = __hip_atomic_load(&aggFlag[j], __ATOMIC_RELAXED,
                                            __HIP_MEMORY_SCOPE_AGENT)) >> 63) == 0)
                __builtin_amdgcn_s_sleep(1);
            sum += (int)(unsigned)(pk & 0xFFFFFFFFULL);
        }
        #pragma unroll
        for (int d = 1; d < 64; d <<= 1) sum += __shfl_xor(sum, d);
        if (threadIdx.x == 0) prefix_s = sum;
    }
    __syncthreads();
    if (gid < N_NODES) {
        int o = prefix_s + s[threadIdx.x] - v;
        offsets[gid] = o;
        cursor[gid] = o;
    }
    if (gid == 0) offsets[N_NODES] = N_EDGES;
}

// ---------------------------------------------------------------------------
// Phase 2c: XCD-partitioned scatter. Consecutive blockIdx round-robin across
// the 8 XCDs, so group g = bid&7 lives on XCD g (perf heuristic only --
// correctness does not depend on the mapping). Group g scans ALL edges but
// scatters only rows in its 1/8 range: each CSR bucket region (~800 KB) is
// then written by ONE XCD, so lines fill while L2-resident and write back
// once. Round 9 measured 8x write amplification (52 MB for 6.4 MB of pairs)
// from all 8 XCDs dirtying partial copies of every line.
// ---------------------------------------------------------------------------
#define SCAT_GROUPS 8
#define SCAT_BPG    392   // blocks per group; grid = 8 * 392 = 3136
__global__ __launch_bounds__(256) void scatter_kernel(
    const int* __restrict__ rows, const int* __restrict__ cols,
    const float* __restrict__ vals, int* __restrict__ cursor,
    int2* __restrict__ pairs)
{
    const int g  = blockIdx.x & (SCAT_GROUPS - 1);
    const int gi = blockIdx.x >> 3;
    const int rowLo = g * (N_NODES / SCAT_GROUPS);
    const int rowHi = rowLo + (N_NODES / SCAT_GROUPS);

    for (int e = gi * 256 + threadIdx.x; e < N_EDGES; e += SCAT_BPG * 256) {
        int r = rows[e];
        if (r >= rowLo && r < rowHi) {
            int p = atomicAdd(&cursor[r], 1);
            int2 pk;
            pk.x = cols[e];
            pk.y = __float_as_int(vals[e]);
            pairs[p] = pk;
        }
    }
}

// ---------------------------------------------------------------------------
// Phase 3: per-row gather-reduce on bf16 support + fused epilogue.
// One wave per row; two 32-lane halves each own 4 bf16 cols (8B gathers),
// processing edges e+half in parallel, 4-deep unroll = 8 gathers in flight;
// cross-half shfl_xor(32) reduce; coalesced float2 store.
// ---------------------------------------------------------------------------
__global__ __launch_bounds__(256) void agg_fused(
    const short* __restrict__ support, const int* __restrict__ offsets,
    const int2* __restrict__ pairs,
    const float* __restrict__ inp, const float* __restrict__ bias,
    const float* __restrict__ alpha, float* __restrict__ out)
{
    const int wv = (blockIdx.x * 256 + threadIdx.x) >> 6;
    const int lane = threadIdx.x & 63;
    if (wv >= N_NODES) return;
    const int half = lane >> 5;
    const int li = lane & 31;

    const int start = offsets[wv];
    const int end   = offsets[wv + 1];

    const float4 x = *(const float4*)&inp[(size_t)wv * D + li * 4];
    const float4 b4 = *(const float4*)&bias[li * 4];
    const float a0 = alpha[0], a1 = alpha[1];

    float4 acc = make_float4(0.f, 0.f, 0.f, 0.f);
    int e = start;
    for (; e + 8 <= end; e += 8) {
        int2 p0 = pairs[e + 0 + half];
        int2 p1 = pairs[e + 2 + half];
        int2 p2 = pairs[e + 4 + half];
        int2 p3 = pairs[e + 6 + half];
        short4v s0 = *(const short4v*)&support[(size_t)p0.x * D + li * 4];
        short4v s1 = *(const short4v*)&support[(size_t)p1.x * D + li * 4];
        short4v s2 = *(const short4v*)&support[(size_t)p2.x * D + li * 4];
        short4v s3 = *(const short4v*)&support[(size_t)p3.x * D + li * 4];
        float v0 = __int_as_float(p0.y), v1 = __int_as_float(p1.y);
        float v2 = __int_as_float(p2.y), v3 = __int_as_float(p3.y);
        acc.x += v0 * bf2f(s0[0]) + v1 * bf2f(s1[0]) + v2 * bf2f(s2[0]) + v3 * bf2f(s3[0]);
        acc.y += v0 * bf2f(s0[1]) + v1 * bf2f(s1[1]) + v2 * bf2f(s2[1]) + v3 * bf2f(s3[1]);
        acc.z += v0 * bf2f(s0[2]) + v1 * bf2f(s1[2]) + v2 * bf2f(s2[2]) + v3 * bf2f(s3[2]);
        acc.w += v0 * bf2f(s0[3]) + v1 * bf2f(s1[3]) + v2 * bf2f(s2[3]) + v3 * bf2f(s3[3]);
    }
    for (; e < end; e += 2) {
        int idx = e + half;
        int2 p = (idx < end) ? pairs[idx] : make_int2(0, 0);   // v=0 when invalid
        float v = __int_as_float(p.y);
        short4v s = *(const short4v*)&support[(size_t)p.x * D + li * 4];
        acc.x += v * bf2f(s[0]);
        acc.y += v * bf2f(s[1]);
        acc.z += v * bf2f(s[2]);
        acc.w += v * bf2f(s[3]);
    }

    acc.x += __shfl_xor(acc.x, 32);
    acc.y += __shfl_xor(acc.y, 32);
    acc.z += __shfl_xor(acc.z, 32);
    acc.w += __shfl_xor(acc.w, 32);

    const float m = fmaxf(a0, a1);
    const float e0 = __expf(a0 - m), e1 = __expf(a1 - m);
    const float inv = 1.f / (e0 + e1);
    const float g0 = e0 * inv, g1 = e1 * inv;

    float t0 = acc.x * g0 + x.x * g1 + b4.x;
    float t1 = acc.y * g0 + x.y * g1 + b4.y;
    float t2 = acc.z * g0 + x.z * g1 + b4.z;
    float t3 = acc.w * g0 + x.w * g1 + b4.w;
    float r0 = t0 > 0.f ? t0 : (__expf(t0) - 1.f);
    float r1 = t1 > 0.f ? t1 : (__expf(t1) - 1.f);
    float r2 = t2 > 0.f ? t2 : (__expf(t2) - 1.f);
    float r3 = t3 > 0.f ? t3 : (__expf(t3) - 1.f);

    float2 o = (half == 0) ? make_float2(r0, r1) : make_float2(r2, r3);
    *(float2*)&out[(size_t)wv * D + li * 4 + half * 2] = o;
}

extern "C" void kernel_launch(void* const* d_in, const int* in_sizes, int n_in,
                              void* d_out, int out_size, void* d_ws, size_t ws_size,
                              hipStream_t stream)
{
    const float* inp   = (const float*)d_in[0];
    const float* W     = (const float*)d_in[1];
    const float* bias  = (const float*)d_in[2];
    const float* alpha = (const float*)d_in[3];
    const float* vals  = (const float*)d_in[4];
    const int*   rows  = (const int*)d_in[5];
    const int*   cols  = (const int*)d_in[6];
    float* out = (float*)d_out;

    // workspace layout (~20 MB; no trailing backslashes in comments)
    short* support  = (short*)d_ws;                            // N*D bf16
    int*   counts   = (int*)(support + (size_t)N_NODES * D);   // N ints (memset)
    int*   ticket   = counts + N_NODES;                        // 1 int (memset)
    // +1 pad keeps aggFlag 8B-aligned (N even, so counts..ticket+pad = even ints)
    unsigned long long* aggFlag = (unsigned long long*)(ticket + 2); // 256 x 8B (memset)
    int*   offsets  = (int*)(aggFlag + 256);                   // N+1 ints
    int*   cursor   = offsets + N_NODES + 1;                   // N ints (+1 pad -> 8B align)
    int2*  pairs    = (int2*)(cursor + N_NODES + 1);           // E pairs, 8B-aligned

    const int nGemmBlocks = (N_NODES + 63) / 64;            // 782
    const int nEdgeBlocks = (N_EDGES + 255) / 256;          // 3125
    const int nScanBlocks = (N_NODES + 255) / 256;          // 196

    // zero counts + ticket + pad + aggFlag in one contiguous memset
    (void)hipMemsetAsync(counts, 0, (size_t)(N_NODES + 2 + 512) * sizeof(int), stream);

    gemm_hist_kernel<<<nGemmBlocks + nEdgeBlocks, 256, 0, stream>>>(
        inp, W, support, rows, counts, nGemmBlocks);
    scan_fused<<<nScanBlocks, 256, 0, stream>>>(counts, offsets, cursor,
                                                aggFlag, ticket);
    scatter_kernel<<<SCAT_GROUPS * SCAT_BPG, 256, 0, stream>>>(
        rows, cols, vals, cursor, pairs);
    agg_fused<<<(N_NODES * 64 + 255) / 256, 256, 0, stream>>>(
        support, offsets, pairs, inp, bias, alpha, out);
}